// Round 8
// baseline (123.637 us; speedup 1.0000x reference)
//
#include <hip/hip_runtime.h>

// ConvSurface: out[m,f,k] = max_s relu( (point_{m,f,s} - center_{m,f}) . W_k + b_k )
// Lane = kernel k (64 = wave64). One wave per FACE, m-loop over 8 meshes.
// R8: R4 dataflow with the SGPR ceiling fixed. R4 hit the ~102-SGPR wave limit
// (beta/gamma pinned 48 SGPRs for the whole kernel) so the compiler could not
// pipeline the next mesh's corner s_loads -> serialized load/drain/compute.
// Now beta/gamma are loaded ONCE per wave via uniform-address vector loads
// into 48 named VGPRs (v_fma with all-VGPR operands is legal), freeing the
// SGPR file for 2-mesh-deep s_load pipelining (unroll 2). Corners/centers
// stay on the SMEM path (readfirstlane face id). No LDS, no arrays.
// Algebra: alpha+beta+gamma==1 => p.W = a1 + beta*(a2-a1) + gamma*(a3-a1);
// bias/center-dot/relu folded outside the sample max (monotone).

#define NM 8
#define NF 16384
#define NK 64

// one neighbor: corner dots from SMEM-resident t[], samples from VGPR bs/gs
#define NEI(MX, T, S0,S1,S2,S3,S4,S5,S6,S7) do { \
    const float a1_ = T[0]*w0 + T[1]*w1 + T[2]*w2; \
    const float a2_ = T[3]*w0 + T[4]*w1 + T[5]*w2; \
    const float a3_ = T[6]*w0 + T[7]*w1 + T[8]*w2; \
    const float e2_ = a2_ - a1_, e3_ = a3_ - a1_; \
    const float v0_ = fmaf(bs##S0, e2_, fmaf(gs##S0, e3_, a1_)); \
    const float v1_ = fmaf(bs##S1, e2_, fmaf(gs##S1, e3_, a1_)); \
    const float v2_ = fmaf(bs##S2, e2_, fmaf(gs##S2, e3_, a1_)); \
    const float v3_ = fmaf(bs##S3, e2_, fmaf(gs##S3, e3_, a1_)); \
    const float v4_ = fmaf(bs##S4, e2_, fmaf(gs##S4, e3_, a1_)); \
    const float v5_ = fmaf(bs##S5, e2_, fmaf(gs##S5, e3_, a1_)); \
    const float v6_ = fmaf(bs##S6, e2_, fmaf(gs##S6, e3_, a1_)); \
    const float v7_ = fmaf(bs##S7, e2_, fmaf(gs##S7, e3_, a1_)); \
    const float p0_ = fmaxf(fmaxf(v0_, v1_), fmaxf(v2_, v3_)); \
    const float p1_ = fmaxf(fmaxf(v4_, v5_), fmaxf(v6_, v7_)); \
    MX = fmaxf(MX, fmaxf(p0_, p1_)); \
} while (0)

__global__ __launch_bounds__(256, 4) void conv_surface_kernel(
    const float* __restrict__ centers,   // [M,F,3]
    const float* __restrict__ nc,        // [M,F,3,3,3]
    const float* __restrict__ beta,      // [F,24]
    const float* __restrict__ gammav,    // [F,24]
    const float* __restrict__ W,         // [64,3]
    const float* __restrict__ b,         // [64]
    float* __restrict__ out)             // [M,F,64]
{
    const int tid  = threadIdx.x;
    const int lane = tid & 63;
    const int fdiv = blockIdx.x * 4 + (tid >> 6);            // per-lane view
    const int funi = __builtin_amdgcn_readfirstlane(fdiv);   // uniform -> SMEM

    // per-lane kernel weights
    const float w0 = W[lane * 3 + 0];
    const float w1 = W[lane * 3 + 1];
    const float w2 = W[lane * 3 + 2];
    const float bk = b[lane];

    // beta/gamma: 12 uniform-address dwordx4 VMEM loads -> 48 named VGPRs.
    // (fdiv, not funi, so these stay on the vector path and OFF the SGPR file)
    const float4* __restrict__ bp4 = (const float4*)(beta   + (size_t)fdiv * 24);
    const float4* __restrict__ gp4 = (const float4*)(gammav + (size_t)fdiv * 24);
    const float4 bqa = bp4[0], bqb = bp4[1], bqc = bp4[2];
    const float4 bqd = bp4[3], bqe = bp4[4], bqf = bp4[5];
    const float4 gqa = gp4[0], gqb = gp4[1], gqc = gp4[2];
    const float4 gqd = gp4[3], gqe = gp4[4], gqf = gp4[5];
    const float bs0 =bqa.x, bs1 =bqa.y, bs2 =bqa.z, bs3 =bqa.w;
    const float bs4 =bqb.x, bs5 =bqb.y, bs6 =bqb.z, bs7 =bqb.w;
    const float bs8 =bqc.x, bs9 =bqc.y, bs10=bqc.z, bs11=bqc.w;
    const float bs12=bqd.x, bs13=bqd.y, bs14=bqd.z, bs15=bqd.w;
    const float bs16=bqe.x, bs17=bqe.y, bs18=bqe.z, bs19=bqe.w;
    const float bs20=bqf.x, bs21=bqf.y, bs22=bqf.z, bs23=bqf.w;
    const float gs0 =gqa.x, gs1 =gqa.y, gs2 =gqa.z, gs3 =gqa.w;
    const float gs4 =gqb.x, gs5 =gqb.y, gs6 =gqb.z, gs7 =gqb.w;
    const float gs8 =gqc.x, gs9 =gqc.y, gs10=gqc.z, gs11=gqc.w;
    const float gs12=gqd.x, gs13=gqd.y, gs14=gqd.z, gs15=gqd.w;
    const float gs16=gqe.x, gs17=gqe.y, gs18=gqe.z, gs19=gqe.w;
    const float gs20=gqf.x, gs21=gqf.y, gs22=gqf.z, gs23=gqf.w;

    // uniform base pointers: corners/centers ride the scalar (SMEM) path
    const float* __restrict__ tbase = nc      + (size_t)funi * 27;
    const float* __restrict__ cbase = centers + (size_t)funi * 3;

#pragma unroll 2
    for (int m = 0; m < NM; ++m) {
        const float* __restrict__ t = tbase + (size_t)m * (NF * 27);
        const float* __restrict__ c = cbase + (size_t)m * (NF * 3);

        const float cdot = c[0] * w0 + c[1] * w1 + c[2] * w2;

        float mx = -3.4e38f;
        NEI(mx, (t + 0), 0, 3, 6, 9, 12, 15, 18, 21);
        NEI(mx, (t + 9), 1, 4, 7, 10, 13, 16, 19, 22);
        NEI(mx, (t + 18), 2, 5, 8, 11, 14, 17, 20, 23);

        out[((size_t)m * NF + fdiv) * NK + lane] = fmaxf(mx + (bk - cdot), 0.0f);
    }
}

extern "C" void kernel_launch(void* const* d_in, const int* in_sizes, int n_in,
                              void* d_out, int out_size, void* d_ws, size_t ws_size,
                              hipStream_t stream) {
    const float* centers = (const float*)d_in[0];
    // d_in[1] = ring_n  (unused by the reference math)
    const float* nc      = (const float*)d_in[2];
    // d_in[3] = alpha   (unused: alpha = 1 - beta - gamma)
    const float* beta    = (const float*)d_in[4];
    const float* gammav  = (const float*)d_in[5];
    const float* W       = (const float*)d_in[6];
    const float* b       = (const float*)d_in[7];
    float* out = (float*)d_out;

    dim3 grid(NF / 4), block(256);   // one wave per face, 8 meshes per wave
    hipLaunchKernelGGL(conv_surface_kernel, grid, block, 0, stream,
                       centers, nc, beta, gammav, W, b, out);
}

// Round 9
// 38.918 us; speedup vs baseline: 3.1769x; 3.1769x over previous
//
#include <hip/hip_runtime.h>

// ConvSurface: out[m,f,k] = max_s relu( (point_{m,f,s} - center_{m,f}) . W_k + b_k )
// Lane = kernel k (64 = wave64). One wave per FACE, m-loop over 8 meshes.
// R9: path swap vs R4. Empirical finding: allocator hard-clamps this kernel at
// 64 VGPRs (any design needing more spills catastrophically: R5/R6/R8). And
// the scalar path (SMEM) cannot stream bulk data: OOO completion forces
// lgkmcnt(0) full drains -> R4 spent ~85% of wave lifetime waiting on K$.
// So: beta/gamma -> SGPRs via one-time SMEM load (48 regs, drained once);
// corners/centers/out -> per-lane VMEM (in-order returns, counted vmcnt,
// deep MSHRs), m-loop fully unrolled so the scheduler pipelines ~2 meshes of
// loads inside the 64-VGPR budget. launch_bounds(256,8) = explicit 64-cap,
// 8 waves/SIMD TLP. All compute state transient SSA scalars; no arrays.
// Algebra: alpha+beta+gamma==1 => p.W = a1 + beta*(a2-a1) + gamma*(a3-a1);
// bias/center-dot/relu folded outside the sample max (monotone).

#define NM 8
#define NF 16384
#define NK 64

// one neighbor: 9 corner floats via T (VMEM), samples from SGPR bs/gs
#define NEI(MX, T, S0,S1,S2,S3,S4,S5,S6,S7) do { \
    const float a1_ = T[0]*w0 + T[1]*w1 + T[2]*w2; \
    const float a2_ = T[3]*w0 + T[4]*w1 + T[5]*w2; \
    const float a3_ = T[6]*w0 + T[7]*w1 + T[8]*w2; \
    const float e2_ = a2_ - a1_, e3_ = a3_ - a1_; \
    const float v0_ = fmaf(bs##S0, e2_, fmaf(gs##S0, e3_, a1_)); \
    const float v1_ = fmaf(bs##S1, e2_, fmaf(gs##S1, e3_, a1_)); \
    const float v2_ = fmaf(bs##S2, e2_, fmaf(gs##S2, e3_, a1_)); \
    const float v3_ = fmaf(bs##S3, e2_, fmaf(gs##S3, e3_, a1_)); \
    const float v4_ = fmaf(bs##S4, e2_, fmaf(gs##S4, e3_, a1_)); \
    const float v5_ = fmaf(bs##S5, e2_, fmaf(gs##S5, e3_, a1_)); \
    const float v6_ = fmaf(bs##S6, e2_, fmaf(gs##S6, e3_, a1_)); \
    const float v7_ = fmaf(bs##S7, e2_, fmaf(gs##S7, e3_, a1_)); \
    const float p0_ = fmaxf(fmaxf(v0_, v1_), v2_); \
    const float p1_ = fmaxf(fmaxf(v3_, v4_), v5_); \
    const float p2_ = fmaxf(fmaxf(v6_, v7_), p0_); \
    MX = fmaxf(MX, fmaxf(p1_, p2_)); \
} while (0)

__global__ __launch_bounds__(256, 8) void conv_surface_kernel(
    const float* __restrict__ centers,   // [M,F,3]
    const float* __restrict__ nc,        // [M,F,3,3,3]
    const float* __restrict__ beta,      // [F,24]
    const float* __restrict__ gammav,    // [F,24]
    const float* __restrict__ W,         // [64,3]
    const float* __restrict__ b,         // [64]
    float* __restrict__ out)             // [M,F,64]
{
    const int tid  = threadIdx.x;
    const int lane = tid & 63;
    const int fdiv = blockIdx.x * 4 + (tid >> 6);            // per-lane -> VMEM
    const int funi = __builtin_amdgcn_readfirstlane(fdiv);   // uniform  -> SMEM

    // per-lane kernel weights (VMEM, tiny, L1-resident)
    const float w0 = W[lane * 3 + 0];
    const float w1 = W[lane * 3 + 1];
    const float w2 = W[lane * 3 + 2];
    const float bk = b[lane];

    // beta/gamma: ONE-TIME scalar loads -> 48 SGPRs, reused for all 8 meshes.
    // (one lgkmcnt drain total; exactly what the scalar path is good at)
    const float* __restrict__ bpp = beta   + (size_t)funi * 24;
    const float* __restrict__ gpp = gammav + (size_t)funi * 24;
    const float bs0 =bpp[0],  bs1 =bpp[1],  bs2 =bpp[2],  bs3 =bpp[3];
    const float bs4 =bpp[4],  bs5 =bpp[5],  bs6 =bpp[6],  bs7 =bpp[7];
    const float bs8 =bpp[8],  bs9 =bpp[9],  bs10=bpp[10], bs11=bpp[11];
    const float bs12=bpp[12], bs13=bpp[13], bs14=bpp[14], bs15=bpp[15];
    const float bs16=bpp[16], bs17=bpp[17], bs18=bpp[18], bs19=bpp[19];
    const float bs20=bpp[20], bs21=bpp[21], bs22=bpp[22], bs23=bpp[23];
    const float gs0 =gpp[0],  gs1 =gpp[1],  gs2 =gpp[2],  gs3 =gpp[3];
    const float gs4 =gpp[4],  gs5 =gpp[5],  gs6 =gpp[6],  gs7 =gpp[7];
    const float gs8 =gpp[8],  gs9 =gpp[9],  gs10=gpp[10], gs11=gpp[11];
    const float gs12=gpp[12], gs13=gpp[13], gs14=gpp[14], gs15=gpp[15];
    const float gs16=gpp[16], gs17=gpp[17], gs18=gpp[18], gs19=gpp[19];
    const float gs20=gpp[20], gs21=gpp[21], gs22=gpp[22], gs23=gpp[23];

    // corners/centers/out: per-lane VMEM bases (uniform-address broadcast
    // loads; in-order returns give the scheduler counted vmcnt pipelining)
    const float* __restrict__ tb = nc      + (size_t)fdiv * 27;
    const float* __restrict__ cb = centers + (size_t)fdiv * 3;
    float* __restrict__       ob = out     + (size_t)fdiv * NK + lane;

#pragma unroll
    for (int m = 0; m < NM; ++m) {
        const float* __restrict__ t = tb + (size_t)m * (NF * 27);
        const float* __restrict__ c = cb + (size_t)m * (NF * 3);

        const float cdot = c[0] * w0 + c[1] * w1 + c[2] * w2;

        float mx = -3.4e38f;
        NEI(mx, (t + 0), 0, 3, 6, 9, 12, 15, 18, 21);
        NEI(mx, (t + 9), 1, 4, 7, 10, 13, 16, 19, 22);
        NEI(mx, (t + 18), 2, 5, 8, 11, 14, 17, 20, 23);

        ob[(size_t)m * (NF * NK)] = fmaxf(mx + (bk - cdot), 0.0f);
    }
}

extern "C" void kernel_launch(void* const* d_in, const int* in_sizes, int n_in,
                              void* d_out, int out_size, void* d_ws, size_t ws_size,
                              hipStream_t stream) {
    const float* centers = (const float*)d_in[0];
    // d_in[1] = ring_n  (unused by the reference math)
    const float* nc      = (const float*)d_in[2];
    // d_in[3] = alpha   (unused: alpha = 1 - beta - gamma)
    const float* beta    = (const float*)d_in[4];
    const float* gammav  = (const float*)d_in[5];
    const float* W       = (const float*)d_in[6];
    const float* b       = (const float*)d_in[7];
    float* out = (float*)d_out;

    dim3 grid(NF / 4), block(256);   // one wave per face, 8 meshes per wave
    hipLaunchKernelGGL(conv_surface_kernel, grid, block, 0, stream,
                       centers, nc, beta, gammav, W, b, out);
}